// Round 4
// baseline (226.976 us; speedup 1.0000x reference)
//
#include <hip/hip_runtime.h>
#include <math.h>

#define HW_ (1024*1024)

__device__ __forceinline__ float wave_red(float a) {
    a += __shfl_xor(a, 1);  a += __shfl_xor(a, 2);  a += __shfl_xor(a, 4);
    a += __shfl_xor(a, 8);  a += __shfl_xor(a, 16); a += __shfl_xor(a, 32);
    return a;
}

// ---------------- fused s0 (3->8, 256^2->128^2) + s1 (8->16, ->64^2) ----------------
// grid (64, B): each block computes an 8x8 tile of s1 output (all 16 ch).
// s0 halo region 17x17x8 computed into LDS first.
__global__ void k_s0s1(const float* __restrict__ lr, const float* __restrict__ sw0,
                       const float* __restrict__ sb0, const float* __restrict__ sw1,
                       const float* __restrict__ sb1, float* __restrict__ ws1)
{
    __shared__ float s0s[8 * 17 * 18];   // [c][y][x-pad18]
    int b = blockIdx.y;
    int ty = blockIdx.x >> 3, tx = blockIdx.x & 7;
    int t = threadIdx.x;

    for (int idx = t; idx < 8 * 289; idx += 256) {
        int c = idx / 289, rem = idx % 289, y = rem / 17, x = rem % 17;
        int gy = 16 * ty - 1 + y, gx = 16 * tx - 1 + x;   // s0 output coords
        float val = 0.f;
        if ((unsigned)gy < 128u && (unsigned)gx < 128u) {
            float acc = sb0[c];
            const float* wp = sw0 + c * 27;
            #pragma unroll
            for (int ci = 0; ci < 3; ci++) {
                const float* ic = lr + (((size_t)b * 3 + ci) << 16);
                #pragma unroll
                for (int kh = 0; kh < 3; kh++) {
                    int hi = 2 * gy - 1 + kh;
                    if ((unsigned)hi >= 256u) continue;
                    #pragma unroll
                    for (int kw = 0; kw < 3; kw++) {
                        int wi = 2 * gx - 1 + kw;
                        if ((unsigned)wi >= 256u) continue;
                        acc += ic[(hi << 8) + wi] * wp[(ci * 3 + kh) * 3 + kw];
                    }
                }
            }
            val = fmaxf(acc, 0.f);
        }
        s0s[c * 306 + y * 18 + x] = val;   // zeros in halo-outside == conv pad semantics
    }
    __syncthreads();

    #pragma unroll
    for (int i = 0; i < 4; i++) {
        int idx = t + (i << 8);            // 1024 outputs: 16ch x 8 x 8
        int c = idx >> 6, y = (idx >> 3) & 7, x = idx & 7;
        float acc = sb1[c];
        const float* wp = sw1 + c * 72;
        for (int ci = 0; ci < 8; ci++) {
            const float* sp = s0s + ci * 306;
            #pragma unroll
            for (int kh = 0; kh < 3; kh++)
                #pragma unroll
                for (int kw = 0; kw < 3; kw++)
                    acc += sp[(2 * y + kh) * 18 + (2 * x + kw)] * wp[(ci * 3 + kh) * 3 + kw];
        }
        ws1[(((size_t)b * 16 + c) * 64 + 8 * ty + y) * 64 + 8 * tx + x] = fmaxf(acc, 0.f);
    }
}

// ---------------- fused s2 (16->32, 64^2->32^2) + s3 (32->64, ->16^2) ----------------
// grid (64, B): each block computes a 2x2 tile of s3 output (all 64 ch).
// s2 halo region 5x5x32 computed into LDS first.
__global__ void k_s2s3(const float* __restrict__ ws1, const float* __restrict__ sw2,
                       const float* __restrict__ sb2, const float* __restrict__ sw3,
                       const float* __restrict__ sb3, float* __restrict__ ws3)
{
    __shared__ float s2s[32 * 25];       // [c][y][x]
    int b = blockIdx.y;
    int ty = blockIdx.x >> 3, tx = blockIdx.x & 7;
    int t = threadIdx.x;

    for (int idx = t; idx < 32 * 25; idx += 256) {
        int c = idx / 25, rem = idx % 25, y = rem / 5, x = rem % 5;
        int gy = 4 * ty - 1 + y, gx = 4 * tx - 1 + x;    // s2 output coords
        float val = 0.f;
        if ((unsigned)gy < 32u && (unsigned)gx < 32u) {
            float acc = sb2[c];
            const float* wp = sw2 + c * 16 * 9;
            for (int ci = 0; ci < 16; ci++) {
                const float* ic = ws1 + ((size_t)b * 16 + ci) * 4096;
                #pragma unroll
                for (int kh = 0; kh < 3; kh++) {
                    int hi = 2 * gy - 1 + kh;
                    if ((unsigned)hi >= 64u) continue;
                    #pragma unroll
                    for (int kw = 0; kw < 3; kw++) {
                        int wi = 2 * gx - 1 + kw;
                        if ((unsigned)wi >= 64u) continue;
                        acc += ic[(hi << 6) + wi] * wp[(ci * 3 + kh) * 3 + kw];
                    }
                }
            }
            val = fmaxf(acc, 0.f);
        }
        s2s[idx] = val;
    }
    __syncthreads();

    {
        int c = t >> 2, y = (t >> 1) & 1, x = t & 1;     // 256 outputs: 64ch x 2 x 2
        float acc = sb3[c];
        const float* wp = sw3 + c * 32 * 9;
        for (int ci = 0; ci < 32; ci++) {
            const float* sp = s2s + ci * 25;
            #pragma unroll
            for (int kh = 0; kh < 3; kh++)
                #pragma unroll
                for (int kw = 0; kw < 3; kw++)
                    acc += sp[(2 * y + kh) * 5 + (2 * x + kw)] * wp[(ci * 3 + kh) * 3 + kw];
        }
        ws3[(((size_t)b * 64 + c) * 16 + 2 * ty + y) * 16 + 2 * tx + x] = fmaxf(acc, 0.f);
    }
}

// -------- 8-way cin-split 3x3 conv body (COUT=64): 32 pixels x 8 cin-groups per block --------
template<int CIN, int S, bool RELU>
__device__ __forceinline__ void conv_split_body(
    const float* __restrict__ in, const float* __restrict__ w,
    const float* __restrict__ bias, float* __restrict__ out,
    int HIN, int WIN, int HOUT, int WOUT, int tile, int co, int b, float* wsm)
{
    constexpr int CPT = CIN / 8;
    int t = threadIdx.x;
    for (int i = t; i < CIN * 9; i += 256) wsm[i] = w[co * CIN * 9 + i];
    __syncthreads();

    int sub = t & 7;
    int pix = tile * 32 + (t >> 3);
    int total_pix = HOUT * WOUT;
    int ho = pix / WOUT, wo = pix % WOUT;
    float acc = 0.f;
    if (pix < total_pix) {
        const float* ip = in + (size_t)b * CIN * HIN * WIN;
        #pragma unroll
        for (int cc = 0; cc < CPT; cc++) {
            int ci = sub * CPT + cc;
            const float* ic = ip + ci * HIN * WIN;
            const float* wr = wsm + ci * 9;
            #pragma unroll
            for (int kh = 0; kh < 3; kh++) {
                int hi = ho * S - 1 + kh;
                if ((unsigned)hi >= (unsigned)HIN) continue;
                #pragma unroll
                for (int kw = 0; kw < 3; kw++) {
                    int wi = wo * S - 1 + kw;
                    if ((unsigned)wi >= (unsigned)WIN) continue;
                    acc += ic[hi * WIN + wi] * wr[kh * 3 + kw];
                }
            }
        }
    }
    acc += __shfl_xor(acc, 1);
    acc += __shfl_xor(acc, 2);
    acc += __shfl_xor(acc, 4);
    if (sub == 0 && pix < total_pix) {
        float r = acc + bias[co];
        if (RELU) r = fmaxf(r, 0.f);
        out[(((size_t)b * 64 + co) * HOUT + ho) * WOUT + wo] = r;
    }
}

// lw0 (stride1 16x16) || gcw0 (stride2 ->8x8), both reading ws3. grid (10, 64, B)
__global__ void k_loc0_gc0(const float* __restrict__ ws3,
                           const float* __restrict__ lw0, const float* __restrict__ lb0,
                           float* __restrict__ loc0,
                           const float* __restrict__ gcw0, const float* __restrict__ gcb0,
                           float* __restrict__ g0)
{
    __shared__ float wsm[576];
    int b = blockIdx.z, co = blockIdx.y;
    if (blockIdx.x < 8)
        conv_split_body<64, 1, true>(ws3, lw0, lb0, loc0, 16, 16, 16, 16, blockIdx.x, co, b, wsm);
    else
        conv_split_body<64, 2, true>(ws3, gcw0, gcb0, g0, 16, 16, 8, 8, blockIdx.x - 8, co, b, wsm);
}

// lw1 (stride1, no relu) || gcw1 (stride2 8->4, relu, writes v in reshape order). grid (9, 64, B)
__global__ void k_loc1_gc1(const float* __restrict__ loc0,
                           const float* __restrict__ lw1, const float* __restrict__ lb1,
                           float* __restrict__ loc,
                           const float* __restrict__ g0,
                           const float* __restrict__ gcw1, const float* __restrict__ gcb1,
                           float* __restrict__ v)
{
    __shared__ float wsm[576];
    int b = blockIdx.z, co = blockIdx.y;
    if (blockIdx.x < 8)
        conv_split_body<64, 1, false>(loc0, lw1, lb1, loc, 16, 16, 16, 16, blockIdx.x, co, b, wsm);
    else
        conv_split_body<64, 2, true>(g0, gcw1, gcb1, v, 8, 8, 4, 4, 0, co, b, wsm);
}

// ------- FC head (redundant per block) + fusion + 1x1 bg conv -> grid[B,8,16,16,12] -------
// grid (16, B): block handles one row r of the 16x16 grid.
__global__ void k_fc_bg(const float* __restrict__ v,
                        const float* __restrict__ fcw0, const float* __restrict__ fcb0,
                        const float* __restrict__ fcw1, const float* __restrict__ fcb1,
                        const float* __restrict__ fcw2, const float* __restrict__ fcb2,
                        const float* __restrict__ loc,
                        const float* __restrict__ bgw, const float* __restrict__ bgb,
                        float* __restrict__ grid_r)
{
    __shared__ float vs[1024];
    __shared__ float h0s[256];
    __shared__ float h1s[128];
    __shared__ float gvs[64];
    __shared__ float fus[1024];          // [64ch][16pix]
    int b = blockIdx.y, r = blockIdx.x;
    int t = threadIdx.x, lane = t & 63, wv = t >> 6;

    ((float4*)vs)[t] = ((const float4*)(v + b * 1024))[t];
    __syncthreads();

    // fc0: 1024 -> 256, wave wv computes outputs [wv*64, wv*64+64)
    for (int i = 0; i < 64; i++) {
        int o = (wv << 6) + i;
        const float4* wr = (const float4*)(fcw0 + o * 1024);
        float acc = 0.f;
        #pragma unroll
        for (int k = 0; k < 4; k++) {
            float4 a = wr[k * 64 + lane];
            float4 x = ((float4*)vs)[k * 64 + lane];
            acc += a.x * x.x + a.y * x.y + a.z * x.z + a.w * x.w;
        }
        acc = wave_red(acc);
        if (lane == 0) h0s[o] = fmaxf(acc + fcb0[o], 0.f);
    }
    __syncthreads();
    // fc1: 256 -> 128
    for (int i = 0; i < 32; i++) {
        int o = (wv << 5) + i;
        float4 a = ((const float4*)(fcw1 + o * 256))[lane];
        float4 x = ((float4*)h0s)[lane];
        float acc = a.x * x.x + a.y * x.y + a.z * x.z + a.w * x.w;
        acc = wave_red(acc);
        if (lane == 0) h1s[o] = fmaxf(acc + fcb1[o], 0.f);
    }
    __syncthreads();
    // fc2: 128 -> 64 (no act)
    for (int i = 0; i < 16; i++) {
        int o = (wv << 4) + i;
        float2 a = ((const float2*)(fcw2 + o * 128))[lane];
        float2 x = ((float2*)h1s)[lane];
        float acc = a.x * x.x + a.y * x.y;
        acc = wave_red(acc);
        if (lane == 0) gvs[o] = acc + fcb2[o];
    }
    __syncthreads();
    // fusion: fused[c][p] = relu(loc[b,c,r,p] + gvs[c])
    #pragma unroll
    for (int i = 0; i < 4; i++) {
        int idx = t + (i << 8);
        int c = idx >> 4, p = idx & 15;
        fus[idx] = fmaxf(loc[(((size_t)b * 64 + c) * 16 + r) * 16 + p] + gvs[c], 0.f);
    }
    __syncthreads();
    // bg 1x1: 96 outputs x 16 pixels; thread t -> pixel t&15, co = (t>>4) + 16*i
    {
        int p = t & 15, cb = t >> 4;
        #pragma unroll
        for (int i = 0; i < 6; i++) {
            int co = cb + (i << 4);
            float acc = bgb[co];
            const float* wr = bgw + co * 64;
            #pragma unroll 8
            for (int k = 0; k < 64; k++) acc += wr[k] * fus[k * 16 + p];
            int c12 = co >> 3, d = co & 7;
            grid_r[(((((size_t)b * 8 + d) * 16 + r) * 16 + p) * 12) + c12] = acc;
        }
    }
}

// ------- fused guide (1x1 convs + sigmoid) + trilinear slice + affine apply -------
__global__ void guide_slice(const float* __restrict__ fr, const float* __restrict__ grid_r,
                            const float* __restrict__ guw0, const float* __restrict__ gub0,
                            const float* __restrict__ guw1, const float* __restrict__ gub1,
                            float* __restrict__ gd_out, float* __restrict__ fin_out)
{
    const int W = 1024;
    int x = blockIdx.x * 64 + (threadIdx.x & 63);
    int y = blockIdx.y * 4 + (threadIdx.x >> 6);
    int b = blockIdx.z;
    int pix = y * W + x;

    const float* frb = fr + (size_t)b * 3 * HW_;
    float r  = frb[pix];
    float g  = frb[HW_ + pix];
    float bl = frb[2 * HW_ + pix];

    float s = gub1[0];
    #pragma unroll
    for (int c = 0; c < 16; c++) {
        float h = guw0[c * 3] * r + guw0[c * 3 + 1] * g + guw0[c * 3 + 2] * bl + gub0[c];
        h = fmaxf(h, 0.f);
        s += guw1[c] * h;
    }
    float gd = 1.f / (1.f + expf(-s));
    gd_out[(size_t)b * HW_ + pix] = gd;

    float xs = (x + 0.5f) * (1.f / 64.f) - 0.5f;
    float ys = (y + 0.5f) * (1.f / 64.f) - 0.5f;
    float fx = floorf(xs), fy = floorf(ys);
    int x0 = min(max((int)fx, 0), 15); int x1 = min(x0 + 1, 15);
    int y0 = min(max((int)fy, 0), 15); int y1 = min(y0 + 1, 15);
    float wx = xs - fx, wy = ys - fy;

    float gz = gd * 8.f - 0.5f;
    float fz = floorf(gz);
    int z0 = min(max((int)fz, 0), 7); int z1 = min(z0 + 1, 7);
    float wz = gz - fz;

    float acc[12];
    #pragma unroll
    for (int c = 0; c < 12; c++) acc[c] = 0.f;

    const float* gb = grid_r + (size_t)b * 8 * 16 * 16 * 12;
    #pragma unroll
    for (int zi = 0; zi < 2; zi++) {
        int z = zi ? z1 : z0;
        float wzf = zi ? wz : 1.f - wz;
        #pragma unroll
        for (int yi = 0; yi < 2; yi++) {
            int yy = yi ? y1 : y0;
            float wyf = wzf * (yi ? wy : 1.f - wy);
            #pragma unroll
            for (int xi = 0; xi < 2; xi++) {
                int xx = xi ? x1 : x0;
                float wf = wyf * (xi ? wx : 1.f - wx);
                const float4* p = (const float4*)(gb + ((z * 16 + yy) * 16 + xx) * 12);
                float4 a0 = p[0], a1 = p[1], a2 = p[2];
                acc[0] += wf * a0.x; acc[1]  += wf * a0.y; acc[2]  += wf * a0.z; acc[3]  += wf * a0.w;
                acc[4] += wf * a1.x; acc[5]  += wf * a1.y; acc[6]  += wf * a1.z; acc[7]  += wf * a1.w;
                acc[8] += wf * a2.x; acc[9]  += wf * a2.y; acc[10] += wf * a2.z; acc[11] += wf * a2.w;
            }
        }
    }

    float o0 = acc[0] * r + acc[1] * g + acc[2]  * bl + acc[3];
    float o1 = acc[4] * r + acc[5] * g + acc[6]  * bl + acc[7];
    float o2 = acc[8] * r + acc[9] * g + acc[10] * bl + acc[11];
    float* fb = fin_out + (size_t)b * 3 * HW_;
    fb[pix] = o0; fb[HW_ + pix] = o1; fb[2 * HW_ + pix] = o2;
}

extern "C" void kernel_launch(void* const* d_in, const int* in_sizes, int n_in,
                              void* d_out, int out_size, void* d_ws, size_t ws_size,
                              hipStream_t stream) {
    const float* lr   = (const float*)d_in[0];
    const float* fr   = (const float*)d_in[1];
    const float* sw0  = (const float*)d_in[2];  const float* sb0 = (const float*)d_in[3];
    const float* sw1  = (const float*)d_in[4];  const float* sb1 = (const float*)d_in[5];
    const float* sw2  = (const float*)d_in[6];  const float* sb2 = (const float*)d_in[7];
    const float* sw3  = (const float*)d_in[8];  const float* sb3 = (const float*)d_in[9];
    const float* lw0  = (const float*)d_in[10]; const float* lb0 = (const float*)d_in[11];
    const float* lw1  = (const float*)d_in[12]; const float* lb1 = (const float*)d_in[13];
    const float* gcw0 = (const float*)d_in[14]; const float* gcb0 = (const float*)d_in[15];
    const float* gcw1 = (const float*)d_in[16]; const float* gcb1 = (const float*)d_in[17];
    const float* fcw0 = (const float*)d_in[18]; const float* fcb0 = (const float*)d_in[19];
    const float* fcw1 = (const float*)d_in[20]; const float* fcb1 = (const float*)d_in[21];
    const float* fcw2 = (const float*)d_in[22]; const float* fcb2 = (const float*)d_in[23];
    const float* bgw  = (const float*)d_in[24]; const float* bgb = (const float*)d_in[25];
    const float* guw0 = (const float*)d_in[26]; const float* gub0 = (const float*)d_in[27];
    const float* guw1 = (const float*)d_in[28]; const float* gub1 = (const float*)d_in[29];

    float* ws = (float*)d_ws;
    float* ws1    = ws;            // [2,16,64,64]   131072
    float* ws3    = ws + 131072;   // [2,64,16,16]   32768
    float* loc0   = ws + 163840;   // [2,64,16,16]   32768
    float* loc    = ws + 196608;   // [2,64,16,16]   32768
    float* g0     = ws + 229376;   // [2,64,8,8]     8192
    float* v      = ws + 237568;   // [2,1024]       2048
    float* grid_r = ws + 239616;   // [2,8,16,16,12] 49152

    float* gd_out  = (float*)d_out;             // [2,1024,1024]
    float* fin_out = (float*)d_out + 2 * HW_;   // [2,3,1024,1024]

    const int B = 2;

    k_s0s1<<<dim3(64, B), 256, 0, stream>>>(lr, sw0, sb0, sw1, sb1, ws1);
    k_s2s3<<<dim3(64, B), 256, 0, stream>>>(ws1, sw2, sb2, sw3, sb3, ws3);
    k_loc0_gc0<<<dim3(10, 64, B), 256, 0, stream>>>(ws3, lw0, lb0, loc0, gcw0, gcb0, g0);
    k_loc1_gc1<<<dim3(9, 64, B), 256, 0, stream>>>(loc0, lw1, lb1, loc, g0, gcw1, gcb1, v);
    k_fc_bg<<<dim3(16, B), 256, 0, stream>>>(v, fcw0, fcb0, fcw1, fcb1, fcw2, fcb2,
                                             loc, bgw, bgb, grid_r);
    guide_slice<<<dim3(16, 256, B), 256, 0, stream>>>(
        fr, grid_r, guw0, gub0, guw1, gub1, gd_out, fin_out);
}

// Round 5
// 139.783 us; speedup vs baseline: 1.6238x; 1.6238x over previous
//
#include <hip/hip_runtime.h>
#include <math.h>

#define HW_ (1024*1024)

__device__ __forceinline__ float wave_red(float a) {
    a += __shfl_xor(a, 1);  a += __shfl_xor(a, 2);  a += __shfl_xor(a, 4);
    a += __shfl_xor(a, 8);  a += __shfl_xor(a, 16); a += __shfl_xor(a, 32);
    return a;
}

// ---------------- fused s0 (3->8, 256^2->128^2) + s1 (8->16, ->64^2) ----------------
// grid (256, B): each block computes a 4x4 tile of s1 output (all 16 ch).
// s0 halo 9x9x8 computed into LDS; sw1 staged in LDS.
__global__ void k_s0s1(const float* __restrict__ lr, const float* __restrict__ sw0,
                       const float* __restrict__ sb0, const float* __restrict__ sw1,
                       const float* __restrict__ sb1, float* __restrict__ ws1)
{
    __shared__ float s0s[8 * 9 * 10];    // [c][y][x pad10]
    __shared__ float w1s[16 * 8 * 9];    // 1152
    int b = blockIdx.y;
    int ty = blockIdx.x >> 4, tx = blockIdx.x & 15;
    int t = threadIdx.x;

    for (int i = t; i < 1152; i += 256) w1s[i] = sw1[i];
    for (int idx = t; idx < 648; idx += 256) {
        int c = idx / 81, rem = idx % 81, y = rem / 9, x = rem % 9;
        int gy = 8 * ty - 1 + y, gx = 8 * tx - 1 + x;    // s0 output coords
        float val = 0.f;
        if ((unsigned)gy < 128u && (unsigned)gx < 128u) {
            float acc = sb0[c];
            const float* wp = sw0 + c * 27;
            #pragma unroll
            for (int ci = 0; ci < 3; ci++) {
                const float* ic = lr + (((size_t)b * 3 + ci) << 16);
                #pragma unroll
                for (int kh = 0; kh < 3; kh++) {
                    int hi = 2 * gy - 1 + kh;
                    if ((unsigned)hi >= 256u) continue;
                    #pragma unroll
                    for (int kw = 0; kw < 3; kw++) {
                        int wi = 2 * gx - 1 + kw;
                        if ((unsigned)wi >= 256u) continue;
                        acc += ic[(hi << 8) + wi] * wp[(ci * 3 + kh) * 3 + kw];
                    }
                }
            }
            val = fmaxf(acc, 0.f);
        }
        s0s[c * 90 + y * 10 + x] = val;
    }
    __syncthreads();

    {   // 256 outputs: 16ch x 4 x 4
        int c = t >> 4, y = (t >> 2) & 3, x = t & 3;
        float acc = sb1[c];
        const float* wp = w1s + c * 72;
        #pragma unroll
        for (int ci = 0; ci < 8; ci++) {
            const float* sp = s0s + ci * 90;
            #pragma unroll
            for (int kh = 0; kh < 3; kh++)
                #pragma unroll
                for (int kw = 0; kw < 3; kw++)
                    acc += sp[(2 * y + kh) * 10 + (2 * x + kw)] * wp[ci * 9 + kh * 3 + kw];
        }
        ws1[(((size_t)b * 16 + c) * 64 + 4 * ty + y) * 64 + 4 * tx + x] = fmaxf(acc, 0.f);
    }
}

// ---------------- fused s2 (16->32, 64^2->32^2) + s3 (32->64, ->16^2) ----------------
// grid (64, B): each block computes a 2x2 tile of s3 output (all 64 ch).
// ws1 input tile (11x11x16) and sw2 staged in LDS; s2 halo 5x5x32 in LDS.
__global__ void k_s2s3(const float* __restrict__ ws1, const float* __restrict__ sw2,
                       const float* __restrict__ sb2, const float* __restrict__ sw3,
                       const float* __restrict__ sb3, float* __restrict__ ws3)
{
    __shared__ float w1t[16 * 11 * 12];  // ws1 tile [ci][y][x pad12], 2112
    __shared__ float w2s[32 * 144];      // 4608
    __shared__ float s2s[32 * 25];       // [c][5][5]
    int b = blockIdx.y;
    int ty = blockIdx.x >> 3, tx = blockIdx.x & 7;
    int t = threadIdx.x;

    for (int i = t; i < 4608; i += 256) w2s[i] = sw2[i];
    for (int idx = t; idx < 16 * 121; idx += 256) {
        int ci = idx / 121, rem = idx % 121, y = rem / 11, x = rem % 11;
        int gy = 8 * ty - 3 + y, gx = 8 * tx - 3 + x;    // ws1 coords
        float val = 0.f;
        if ((unsigned)gy < 64u && (unsigned)gx < 64u)
            val = ws1[(((size_t)b * 16 + ci) << 12) + (gy << 6) + gx];
        w1t[ci * 132 + y * 12 + x] = val;
    }
    __syncthreads();

    for (int idx = t; idx < 800; idx += 256) {
        int c = idx / 25, rem = idx % 25, y = rem / 5, x = rem % 5;
        int gy = 4 * ty - 1 + y, gx = 4 * tx - 1 + x;    // s2 output coords
        float val = 0.f;
        if ((unsigned)gy < 32u && (unsigned)gx < 32u) {
            float acc = sb2[c];
            const float* wp = w2s + c * 144;
            #pragma unroll
            for (int ci = 0; ci < 16; ci++) {
                const float* sp = w1t + ci * 132;
                #pragma unroll
                for (int kh = 0; kh < 3; kh++)
                    #pragma unroll
                    for (int kw = 0; kw < 3; kw++)
                        acc += sp[(2 * y + kh) * 12 + (2 * x + kw)] * wp[ci * 9 + kh * 3 + kw];
            }
            val = fmaxf(acc, 0.f);
        }
        s2s[idx] = val;
    }
    __syncthreads();

    {   // 256 outputs: 64ch x 2 x 2
        int c = t >> 2, y = (t >> 1) & 1, x = t & 1;
        float acc = sb3[c];
        const float* wp = sw3 + c * 288;
        #pragma unroll 4
        for (int ci = 0; ci < 32; ci++) {
            const float* sp = s2s + ci * 25;
            #pragma unroll
            for (int kh = 0; kh < 3; kh++)
                #pragma unroll
                for (int kw = 0; kw < 3; kw++)
                    acc += sp[(2 * y + kh) * 5 + (2 * x + kw)] * wp[ci * 9 + kh * 3 + kw];
        }
        ws3[(((size_t)b * 64 + c) * 16 + 2 * ty + y) * 16 + 2 * tx + x] = fmaxf(acc, 0.f);
    }
}

// -------- 8-way cin-split 3x3 conv body (COUT=64): 32 pixels x 8 cin-groups per block --------
template<int CIN, int S, bool RELU>
__device__ __forceinline__ void conv_split_body(
    const float* __restrict__ in, const float* __restrict__ w,
    const float* __restrict__ bias, float* __restrict__ out,
    int HIN, int WIN, int HOUT, int WOUT, int tile, int co, int b, float* wsm)
{
    constexpr int CPT = CIN / 8;
    int t = threadIdx.x;
    for (int i = t; i < CIN * 9; i += 256) wsm[i] = w[co * CIN * 9 + i];
    __syncthreads();

    int sub = t & 7;
    int pix = tile * 32 + (t >> 3);
    int total_pix = HOUT * WOUT;
    int ho = pix / WOUT, wo = pix % WOUT;
    float acc = 0.f;
    if (pix < total_pix) {
        const float* ip = in + (size_t)b * CIN * HIN * WIN;
        #pragma unroll
        for (int cc = 0; cc < CPT; cc++) {
            int ci = sub * CPT + cc;
            const float* ic = ip + ci * HIN * WIN;
            const float* wr = wsm + ci * 9;
            #pragma unroll
            for (int kh = 0; kh < 3; kh++) {
                int hi = ho * S - 1 + kh;
                if ((unsigned)hi >= (unsigned)HIN) continue;
                #pragma unroll
                for (int kw = 0; kw < 3; kw++) {
                    int wi = wo * S - 1 + kw;
                    if ((unsigned)wi >= (unsigned)WIN) continue;
                    acc += ic[hi * WIN + wi] * wr[kh * 3 + kw];
                }
            }
        }
    }
    acc += __shfl_xor(acc, 1);
    acc += __shfl_xor(acc, 2);
    acc += __shfl_xor(acc, 4);
    if (sub == 0 && pix < total_pix) {
        float r = acc + bias[co];
        if (RELU) r = fmaxf(r, 0.f);
        out[(((size_t)b * 64 + co) * HOUT + ho) * WOUT + wo] = r;
    }
}

// lw0 (stride1 16x16) || gcw0 (stride2 ->8x8). grid (10, 64, B)
__global__ void k_loc0_gc0(const float* __restrict__ ws3,
                           const float* __restrict__ lw0, const float* __restrict__ lb0,
                           float* __restrict__ loc0,
                           const float* __restrict__ gcw0, const float* __restrict__ gcb0,
                           float* __restrict__ g0)
{
    __shared__ float wsm[576];
    int b = blockIdx.z, co = blockIdx.y;
    if (blockIdx.x < 8)
        conv_split_body<64, 1, true>(ws3, lw0, lb0, loc0, 16, 16, 16, 16, blockIdx.x, co, b, wsm);
    else
        conv_split_body<64, 2, true>(ws3, gcw0, gcb0, g0, 16, 16, 8, 8, blockIdx.x - 8, co, b, wsm);
}

// lw1 (stride1, no relu) || gcw1 (stride2 8->4, relu, writes v in reshape order). grid (9, 64, B)
__global__ void k_loc1_gc1(const float* __restrict__ loc0,
                           const float* __restrict__ lw1, const float* __restrict__ lb1,
                           float* __restrict__ loc,
                           const float* __restrict__ g0,
                           const float* __restrict__ gcw1, const float* __restrict__ gcb1,
                           float* __restrict__ v)
{
    __shared__ float wsm[576];
    int b = blockIdx.z, co = blockIdx.y;
    if (blockIdx.x < 8)
        conv_split_body<64, 1, false>(loc0, lw1, lb1, loc, 16, 16, 16, 16, blockIdx.x, co, b, wsm);
    else
        conv_split_body<64, 2, true>(g0, gcw1, gcb1, v, 8, 8, 4, 4, 0, co, b, wsm);
}

// -------- FC0: wave-per-output GEMV 1024 -> 256, relu. grid 128 x 256thr --------
__global__ void k_fc0(const float* __restrict__ in, const float* __restrict__ w,
                      const float* __restrict__ bias, float* __restrict__ out)
{
    int gw = (blockIdx.x * blockDim.x + threadIdx.x) >> 6;   // [0, 512)
    int lane = threadIdx.x & 63;
    int b = gw >> 8, o = gw & 255;
    const float4* wr = (const float4*)(w + o * 1024);
    const float4* vr = (const float4*)(in + b * 1024);
    float acc = 0.f;
    #pragma unroll
    for (int i = 0; i < 4; i++) {
        float4 a = wr[i * 64 + lane];
        float4 x = vr[i * 64 + lane];
        acc += a.x * x.x + a.y * x.y + a.z * x.z + a.w * x.w;
    }
    acc = wave_red(acc);
    if (lane == 0) out[b * 256 + o] = fmaxf(acc + bias[o], 0.f);
}

// ------- fc1+fc2 (redundant per block) + fusion + 1x1 bg conv -> grid[B,8,16,16,12] -------
// grid (16, B): block handles one row r of the 16x16 grid. 256 threads.
__global__ void k_fc12_bg(const float* __restrict__ h0,
                          const float* __restrict__ fcw1, const float* __restrict__ fcb1,
                          const float* __restrict__ fcw2, const float* __restrict__ fcb2,
                          const float* __restrict__ loc,
                          const float* __restrict__ bgw, const float* __restrict__ bgb,
                          float* __restrict__ grid_r)
{
    __shared__ float h0s[256];
    __shared__ float h1s[128];
    __shared__ float gvs[64];
    __shared__ float fus[1024];          // [64ch][16pix]
    int b = blockIdx.y, r = blockIdx.x;
    int t = threadIdx.x, lane = t & 63, wv = t >> 6;

    h0s[t] = h0[b * 256 + t];
    __syncthreads();
    // fc1: 256 -> 128, 32 outputs per wave
    #pragma unroll 2
    for (int i = 0; i < 32; i++) {
        int o = (wv << 5) + i;
        float4 a = ((const float4*)(fcw1 + o * 256))[lane];
        float4 x = ((float4*)h0s)[lane];
        float acc = a.x * x.x + a.y * x.y + a.z * x.z + a.w * x.w;
        acc = wave_red(acc);
        if (lane == 0) h1s[o] = fmaxf(acc + fcb1[o], 0.f);
    }
    __syncthreads();
    // fc2: 128 -> 64 (no act), 16 outputs per wave
    #pragma unroll 2
    for (int i = 0; i < 16; i++) {
        int o = (wv << 4) + i;
        float2 a = ((const float2*)(fcw2 + o * 128))[lane];
        float2 x = ((float2*)h1s)[lane];
        float acc = a.x * x.x + a.y * x.y;
        acc = wave_red(acc);
        if (lane == 0) gvs[o] = acc + fcb2[o];
    }
    __syncthreads();
    // fusion: fus[c][p] = relu(loc[b,c,r,p] + gvs[c])
    #pragma unroll
    for (int i = 0; i < 4; i++) {
        int idx = t + (i << 8);
        int c = idx >> 4, p = idx & 15;
        fus[idx] = fmaxf(loc[(((size_t)b * 64 + c) * 16 + r) * 16 + p] + gvs[c], 0.f);
    }
    __syncthreads();
    // bg 1x1 with fus-reuse: thread t -> pixel p=t&15, co = (t>>4) + 16*j, j=0..5
    {
        int p = t & 15, cg = t >> 4;
        float acc6[6];
        #pragma unroll
        for (int j = 0; j < 6; j++) acc6[j] = bgb[cg + (j << 4)];
        #pragma unroll 8
        for (int k = 0; k < 64; k++) {
            float f = fus[k * 16 + p];
            #pragma unroll
            for (int j = 0; j < 6; j++)
                acc6[j] += bgw[(cg + (j << 4)) * 64 + k] * f;
        }
        #pragma unroll
        for (int j = 0; j < 6; j++) {
            int co = cg + (j << 4);
            int c12 = co >> 3, d = co & 7;
            grid_r[(((((size_t)b * 8 + d) * 16 + r) * 16 + p) * 12) + c12] = acc6[j];
        }
    }
}

// ------- fused guide (1x1 convs + sigmoid) + trilinear slice + affine apply -------
__global__ void guide_slice(const float* __restrict__ fr, const float* __restrict__ grid_r,
                            const float* __restrict__ guw0, const float* __restrict__ gub0,
                            const float* __restrict__ guw1, const float* __restrict__ gub1,
                            float* __restrict__ gd_out, float* __restrict__ fin_out)
{
    const int W = 1024;
    int x = blockIdx.x * 64 + (threadIdx.x & 63);
    int y = blockIdx.y * 4 + (threadIdx.x >> 6);
    int b = blockIdx.z;
    int pix = y * W + x;

    const float* frb = fr + (size_t)b * 3 * HW_;
    float r  = frb[pix];
    float g  = frb[HW_ + pix];
    float bl = frb[2 * HW_ + pix];

    float s = gub1[0];
    #pragma unroll
    for (int c = 0; c < 16; c++) {
        float h = guw0[c * 3] * r + guw0[c * 3 + 1] * g + guw0[c * 3 + 2] * bl + gub0[c];
        h = fmaxf(h, 0.f);
        s += guw1[c] * h;
    }
    float gd = 1.f / (1.f + expf(-s));
    gd_out[(size_t)b * HW_ + pix] = gd;

    float xs = (x + 0.5f) * (1.f / 64.f) - 0.5f;
    float ys = (y + 0.5f) * (1.f / 64.f) - 0.5f;
    float fx = floorf(xs), fy = floorf(ys);
    int x0 = min(max((int)fx, 0), 15); int x1 = min(x0 + 1, 15);
    int y0 = min(max((int)fy, 0), 15); int y1 = min(y0 + 1, 15);
    float wx = xs - fx, wy = ys - fy;

    float gz = gd * 8.f - 0.5f;
    float fz = floorf(gz);
    int z0 = min(max((int)fz, 0), 7); int z1 = min(z0 + 1, 7);
    float wz = gz - fz;

    float acc[12];
    #pragma unroll
    for (int c = 0; c < 12; c++) acc[c] = 0.f;

    const float* gb = grid_r + (size_t)b * 8 * 16 * 16 * 12;
    #pragma unroll
    for (int zi = 0; zi < 2; zi++) {
        int z = zi ? z1 : z0;
        float wzf = zi ? wz : 1.f - wz;
        #pragma unroll
        for (int yi = 0; yi < 2; yi++) {
            int yy = yi ? y1 : y0;
            float wyf = wzf * (yi ? wy : 1.f - wy);
            #pragma unroll
            for (int xi = 0; xi < 2; xi++) {
                int xx = xi ? x1 : x0;
                float wf = wyf * (xi ? wx : 1.f - wx);
                const float4* p = (const float4*)(gb + ((z * 16 + yy) * 16 + xx) * 12);
                float4 a0 = p[0], a1 = p[1], a2 = p[2];
                acc[0] += wf * a0.x; acc[1]  += wf * a0.y; acc[2]  += wf * a0.z; acc[3]  += wf * a0.w;
                acc[4] += wf * a1.x; acc[5]  += wf * a1.y; acc[6]  += wf * a1.z; acc[7]  += wf * a1.w;
                acc[8] += wf * a2.x; acc[9]  += wf * a2.y; acc[10] += wf * a2.z; acc[11] += wf * a2.w;
            }
        }
    }

    float o0 = acc[0] * r + acc[1] * g + acc[2]  * bl + acc[3];
    float o1 = acc[4] * r + acc[5] * g + acc[6]  * bl + acc[7];
    float o2 = acc[8] * r + acc[9] * g + acc[10] * bl + acc[11];
    float* fb = fin_out + (size_t)b * 3 * HW_;
    fb[pix] = o0; fb[HW_ + pix] = o1; fb[2 * HW_ + pix] = o2;
}

extern "C" void kernel_launch(void* const* d_in, const int* in_sizes, int n_in,
                              void* d_out, int out_size, void* d_ws, size_t ws_size,
                              hipStream_t stream) {
    const float* lr   = (const float*)d_in[0];
    const float* fr   = (const float*)d_in[1];
    const float* sw0  = (const float*)d_in[2];  const float* sb0 = (const float*)d_in[3];
    const float* sw1  = (const float*)d_in[4];  const float* sb1 = (const float*)d_in[5];
    const float* sw2  = (const float*)d_in[6];  const float* sb2 = (const float*)d_in[7];
    const float* sw3  = (const float*)d_in[8];  const float* sb3 = (const float*)d_in[9];
    const float* lw0  = (const float*)d_in[10]; const float* lb0 = (const float*)d_in[11];
    const float* lw1  = (const float*)d_in[12]; const float* lb1 = (const float*)d_in[13];
    const float* gcw0 = (const float*)d_in[14]; const float* gcb0 = (const float*)d_in[15];
    const float* gcw1 = (const float*)d_in[16]; const float* gcb1 = (const float*)d_in[17];
    const float* fcw0 = (const float*)d_in[18]; const float* fcb0 = (const float*)d_in[19];
    const float* fcw1 = (const float*)d_in[20]; const float* fcb1 = (const float*)d_in[21];
    const float* fcw2 = (const float*)d_in[22]; const float* fcb2 = (const float*)d_in[23];
    const float* bgw  = (const float*)d_in[24]; const float* bgb = (const float*)d_in[25];
    const float* guw0 = (const float*)d_in[26]; const float* gub0 = (const float*)d_in[27];
    const float* guw1 = (const float*)d_in[28]; const float* gub1 = (const float*)d_in[29];

    float* ws = (float*)d_ws;
    float* ws1    = ws;            // [2,16,64,64]   131072
    float* ws3    = ws + 131072;   // [2,64,16,16]   32768
    float* loc0   = ws + 163840;   // [2,64,16,16]   32768
    float* loc    = ws + 196608;   // [2,64,16,16]   32768
    float* g0     = ws + 229376;   // [2,64,8,8]     8192
    float* v      = ws + 237568;   // [2,1024]       2048
    float* h0     = ws + 239616;   // [2,256]        512
    float* grid_r = ws + 240128;   // [2,8,16,16,12] 49152

    float* gd_out  = (float*)d_out;             // [2,1024,1024]
    float* fin_out = (float*)d_out + 2 * HW_;   // [2,3,1024,1024]

    const int B = 2;

    k_s0s1<<<dim3(256, B), 256, 0, stream>>>(lr, sw0, sb0, sw1, sb1, ws1);
    k_s2s3<<<dim3(64, B), 256, 0, stream>>>(ws1, sw2, sb2, sw3, sb3, ws3);
    k_loc0_gc0<<<dim3(10, 64, B), 256, 0, stream>>>(ws3, lw0, lb0, loc0, gcw0, gcb0, g0);
    k_loc1_gc1<<<dim3(9, 64, B), 256, 0, stream>>>(loc0, lw1, lb1, loc, g0, gcw1, gcb1, v);
    k_fc0<<<dim3(128), 256, 0, stream>>>(v, fcw0, fcb0, h0);
    k_fc12_bg<<<dim3(16, B), 256, 0, stream>>>(h0, fcw1, fcb1, fcw2, fcb2,
                                               loc, bgw, bgb, grid_r);
    guide_slice<<<dim3(16, 256, B), 256, 0, stream>>>(
        fr, grid_r, guw0, gub0, guw1, gub1, gd_out, fin_out);
}

// Round 6
// 137.229 us; speedup vs baseline: 1.6540x; 1.0186x over previous
//
#include <hip/hip_runtime.h>
#include <math.h>

#define HW_ (1024*1024)

__device__ __forceinline__ float wave_red(float a) {
    a += __shfl_xor(a, 1);  a += __shfl_xor(a, 2);  a += __shfl_xor(a, 4);
    a += __shfl_xor(a, 8);  a += __shfl_xor(a, 16); a += __shfl_xor(a, 32);
    return a;
}

// ---------------- fused s0 (3->8, 256^2->128^2) + s1 (8->16, ->64^2) ----------------
// grid (256, B): each block computes a 4x4 tile of s1 output (all 16 ch).
__global__ void k_s0s1(const float* __restrict__ lr, const float* __restrict__ sw0,
                       const float* __restrict__ sb0, const float* __restrict__ sw1,
                       const float* __restrict__ sb1, float* __restrict__ ws1)
{
    __shared__ float s0s[8 * 9 * 10];    // [c][y][x pad10]
    __shared__ float w1s[16 * 8 * 9];    // 1152
    int b = blockIdx.y;
    int ty = blockIdx.x >> 4, tx = blockIdx.x & 15;
    int t = threadIdx.x;

    for (int i = t; i < 1152; i += 256) w1s[i] = sw1[i];
    for (int idx = t; idx < 648; idx += 256) {
        int c = idx / 81, rem = idx % 81, y = rem / 9, x = rem % 9;
        int gy = 8 * ty - 1 + y, gx = 8 * tx - 1 + x;    // s0 output coords
        float val = 0.f;
        if ((unsigned)gy < 128u && (unsigned)gx < 128u) {
            float acc = sb0[c];
            const float* wp = sw0 + c * 27;
            #pragma unroll
            for (int ci = 0; ci < 3; ci++) {
                const float* ic = lr + (((size_t)b * 3 + ci) << 16);
                #pragma unroll
                for (int kh = 0; kh < 3; kh++) {
                    int hi = 2 * gy - 1 + kh;
                    if ((unsigned)hi >= 256u) continue;
                    #pragma unroll
                    for (int kw = 0; kw < 3; kw++) {
                        int wi = 2 * gx - 1 + kw;
                        if ((unsigned)wi >= 256u) continue;
                        acc += ic[(hi << 8) + wi] * wp[(ci * 3 + kh) * 3 + kw];
                    }
                }
            }
            val = fmaxf(acc, 0.f);
        }
        s0s[c * 90 + y * 10 + x] = val;
    }
    __syncthreads();

    {   // 256 outputs: 16ch x 4 x 4
        int c = t >> 4, y = (t >> 2) & 3, x = t & 3;
        float acc = sb1[c];
        const float* wp = w1s + c * 72;
        #pragma unroll
        for (int ci = 0; ci < 8; ci++) {
            const float* sp = s0s + ci * 90;
            #pragma unroll
            for (int kh = 0; kh < 3; kh++)
                #pragma unroll
                for (int kw = 0; kw < 3; kw++)
                    acc += sp[(2 * y + kh) * 10 + (2 * x + kw)] * wp[ci * 9 + kh * 3 + kw];
        }
        ws1[(((size_t)b * 16 + c) * 64 + 4 * ty + y) * 64 + 4 * tx + x] = fmaxf(acc, 0.f);
    }
}

// ---------------- fused s2 (16->32, 64^2->32^2) + s3 (32->64, ->16^2) ----------------
// grid (64, B): each block computes a 2x2 tile of s3 output (all 64 ch).
// All weights flow through LDS: wbuf holds sw2 first, then sw3 in 4 chunks (pad-73 rows).
__global__ void k_s2s3(const float* __restrict__ ws1, const float* __restrict__ sw2,
                       const float* __restrict__ sb2, const float* __restrict__ sw3,
                       const float* __restrict__ sb3, float* __restrict__ ws3)
{
    __shared__ float w1t[16 * 132];      // ws1 tile [ci][11][12]
    __shared__ float wbuf[4672];         // sw2 (4608) then sw3 chunk (64 rows x pad73)
    __shared__ float s2s[800];           // [32][5][5]
    int b = blockIdx.y;
    int ty = blockIdx.x >> 3, tx = blockIdx.x & 7;
    int t = threadIdx.x;

    for (int i = t; i < 4608; i += 256) wbuf[i] = sw2[i];
    for (int idx = t; idx < 16 * 121; idx += 256) {
        int ci = idx / 121, rem = idx % 121, y = rem / 11, x = rem % 11;
        int gy = 8 * ty - 3 + y, gx = 8 * tx - 3 + x;    // ws1 coords
        float val = 0.f;
        if ((unsigned)gy < 64u && (unsigned)gx < 64u)
            val = ws1[(((size_t)b * 16 + ci) << 12) + (gy << 6) + gx];
        w1t[ci * 132 + y * 12 + x] = val;
    }
    __syncthreads();

    for (int idx = t; idx < 800; idx += 256) {
        int c = idx / 25, rem = idx % 25, y = rem / 5, x = rem % 5;
        int gy = 4 * ty - 1 + y, gx = 4 * tx - 1 + x;    // s2 output coords
        float val = 0.f;
        if ((unsigned)gy < 32u && (unsigned)gx < 32u) {
            float acc = sb2[c];
            const float* wp = wbuf + c * 144;
            #pragma unroll
            for (int ci = 0; ci < 16; ci++) {
                const float* sp = w1t + ci * 132;
                #pragma unroll
                for (int kh = 0; kh < 3; kh++)
                    #pragma unroll
                    for (int kw = 0; kw < 3; kw++)
                        acc += sp[(2 * y + kh) * 12 + (2 * x + kw)] * wp[ci * 9 + kh * 3 + kw];
            }
            val = fmaxf(acc, 0.f);
        }
        s2s[idx] = val;
    }
    __syncthreads();

    // s3 stage: one output per thread (64ch x 2 x 2), sw3 via LDS in 4 ci-chunks of 8
    int c = t >> 2, y = (t >> 1) & 1, x = t & 1;
    float acc = sb3[c];
    for (int cc = 0; cc < 4; cc++) {
        for (int i = t; i < 4608; i += 256) {
            int co = i / 72, rem = i % 72;
            wbuf[co * 73 + rem] = sw3[co * 288 + cc * 72 + rem];
        }
        __syncthreads();
        const float* wp = wbuf + c * 73;
        #pragma unroll
        for (int ci8 = 0; ci8 < 8; ci8++) {
            const float* sp = s2s + (cc * 8 + ci8) * 25;
            #pragma unroll
            for (int kh = 0; kh < 3; kh++)
                #pragma unroll
                for (int kw = 0; kw < 3; kw++)
                    acc += sp[(2 * y + kh) * 5 + (2 * x + kw)] * wp[ci8 * 9 + kh * 3 + kw];
        }
        __syncthreads();
    }
    ws3[(((size_t)b * 64 + c) * 16 + 2 * ty + y) * 16 + 2 * tx + x] = fmaxf(acc, 0.f);
}

// -------- 8-way cin-split 3x3 conv body (COUT=64): 32 pixels x 8 cin-groups per block --------
template<int CIN, int S, bool RELU>
__device__ __forceinline__ void conv_split_body(
    const float* __restrict__ in, const float* __restrict__ w,
    const float* __restrict__ bias, float* __restrict__ out,
    int HIN, int WIN, int HOUT, int WOUT, int tile, int co, int b, float* wsm)
{
    constexpr int CPT = CIN / 8;
    int t = threadIdx.x;
    for (int i = t; i < CIN * 9; i += 256) wsm[i] = w[co * CIN * 9 + i];
    __syncthreads();

    int sub = t & 7;
    int pix = tile * 32 + (t >> 3);
    int total_pix = HOUT * WOUT;
    int ho = pix / WOUT, wo = pix % WOUT;
    float acc = 0.f;
    if (pix < total_pix) {
        const float* ip = in + (size_t)b * CIN * HIN * WIN;
        #pragma unroll
        for (int cc = 0; cc < CPT; cc++) {
            int ci = sub * CPT + cc;
            const float* ic = ip + ci * HIN * WIN;
            const float* wr = wsm + ci * 9;
            #pragma unroll
            for (int kh = 0; kh < 3; kh++) {
                int hi = ho * S - 1 + kh;
                if ((unsigned)hi >= (unsigned)HIN) continue;
                #pragma unroll
                for (int kw = 0; kw < 3; kw++) {
                    int wi = wo * S - 1 + kw;
                    if ((unsigned)wi >= (unsigned)WIN) continue;
                    acc += ic[hi * WIN + wi] * wr[kh * 3 + kw];
                }
            }
        }
    }
    acc += __shfl_xor(acc, 1);
    acc += __shfl_xor(acc, 2);
    acc += __shfl_xor(acc, 4);
    if (sub == 0 && pix < total_pix) {
        float r = acc + bias[co];
        if (RELU) r = fmaxf(r, 0.f);
        out[(((size_t)b * 64 + co) * HOUT + ho) * WOUT + wo] = r;
    }
}

// lw0 (stride1 16x16) || gcw0 (stride2 ->8x8). grid (10, 64, B)
__global__ void k_loc0_gc0(const float* __restrict__ ws3,
                           const float* __restrict__ lw0, const float* __restrict__ lb0,
                           float* __restrict__ loc0,
                           const float* __restrict__ gcw0, const float* __restrict__ gcb0,
                           float* __restrict__ g0)
{
    __shared__ float wsm[576];
    int b = blockIdx.z, co = blockIdx.y;
    if (blockIdx.x < 8)
        conv_split_body<64, 1, true>(ws3, lw0, lb0, loc0, 16, 16, 16, 16, blockIdx.x, co, b, wsm);
    else
        conv_split_body<64, 2, true>(ws3, gcw0, gcb0, g0, 16, 16, 8, 8, blockIdx.x - 8, co, b, wsm);
}

// lw1 (stride1, no relu) || gcw1 (stride2 8->4, relu, writes v in reshape order). grid (9, 64, B)
__global__ void k_loc1_gc1(const float* __restrict__ loc0,
                           const float* __restrict__ lw1, const float* __restrict__ lb1,
                           float* __restrict__ loc,
                           const float* __restrict__ g0,
                           const float* __restrict__ gcw1, const float* __restrict__ gcb1,
                           float* __restrict__ v)
{
    __shared__ float wsm[576];
    int b = blockIdx.z, co = blockIdx.y;
    if (blockIdx.x < 8)
        conv_split_body<64, 1, false>(loc0, lw1, lb1, loc, 16, 16, 16, 16, blockIdx.x, co, b, wsm);
    else
        conv_split_body<64, 2, true>(g0, gcw1, gcb1, v, 8, 8, 4, 4, 0, co, b, wsm);
}

// -------- FC0: wave-per-output GEMV 1024 -> 256, relu. grid 128 x 256thr --------
__global__ void k_fc0(const float* __restrict__ in, const float* __restrict__ w,
                      const float* __restrict__ bias, float* __restrict__ out)
{
    int gw = (blockIdx.x * blockDim.x + threadIdx.x) >> 6;   // [0, 512)
    int lane = threadIdx.x & 63;
    int b = gw >> 8, o = gw & 255;
    const float4* wr = (const float4*)(w + o * 1024);
    const float4* vr = (const float4*)(in + b * 1024);
    float acc = 0.f;
    #pragma unroll
    for (int i = 0; i < 4; i++) {
        float4 a = wr[i * 64 + lane];
        float4 x = vr[i * 64 + lane];
        acc += a.x * x.x + a.y * x.y + a.z * x.z + a.w * x.w;
    }
    acc = wave_red(acc);
    if (lane == 0) out[b * 256 + o] = fmaxf(acc + bias[o], 0.f);
}

// -------- FC1: 256 -> 128, relu. grid (8, B): block j owns outputs [16j, 16j+16) --------
__global__ void k_fc1(const float* __restrict__ h0, const float* __restrict__ fcw1,
                      const float* __restrict__ fcb1, float* __restrict__ h1)
{
    __shared__ float h0s[256];
    int b = blockIdx.y, j = blockIdx.x;
    int t = threadIdx.x, lane = t & 63, wv = t >> 6;
    h0s[t] = h0[b * 256 + t];
    __syncthreads();
    float4 x = ((float4*)h0s)[lane];
    #pragma unroll
    for (int i = 0; i < 4; i++) {
        int o = j * 16 + wv * 4 + i;
        float4 a = ((const float4*)(fcw1 + o * 256))[lane];
        float acc = a.x * x.x + a.y * x.y + a.z * x.z + a.w * x.w;
        acc = wave_red(acc);
        if (lane == 0) h1[b * 128 + o] = fmaxf(acc + fcb1[o], 0.f);
    }
}

// ------- fc2 (redundant, coalesced) + fusion + 1x1 bg conv (bgw in LDS, pad-65) -------
// grid (16, B): block handles one row r of the 16x16 grid. 256 threads.
__global__ void k_fc2bg(const float* __restrict__ h1in,
                        const float* __restrict__ fcw2, const float* __restrict__ fcb2,
                        const float* __restrict__ loc,
                        const float* __restrict__ bgw, const float* __restrict__ bgb,
                        float* __restrict__ grid_r)
{
    __shared__ float h1s[128];
    __shared__ float gvs[64];
    __shared__ float fus[1024];          // [64ch][16pix]
    __shared__ float bgws[96 * 65];      // pad-65 rows: conflict-free column reads
    int b = blockIdx.y, r = blockIdx.x;
    int t = threadIdx.x, lane = t & 63, wv = t >> 6;

    if (t < 128) h1s[t] = h1in[b * 128 + t];
    for (int i = t; i < 6144; i += 256) bgws[(i >> 6) * 65 + (i & 63)] = bgw[i];
    __syncthreads();

    // fc2: 128 -> 64 (no act), 16 outputs per wave, coalesced global rows
    {
        float2 x = ((float2*)h1s)[lane];
        #pragma unroll 4
        for (int i = 0; i < 16; i++) {
            int o = (wv << 4) + i;
            float2 a = ((const float2*)(fcw2 + o * 128))[lane];
            float acc = a.x * x.x + a.y * x.y;
            acc = wave_red(acc);
            if (lane == 0) gvs[o] = acc + fcb2[o];
        }
    }
    __syncthreads();
    // fusion: fus[c][p] = relu(loc[b,c,r,p] + gvs[c])
    #pragma unroll
    for (int i = 0; i < 4; i++) {
        int idx = t + (i << 8);
        int c = idx >> 4, p = idx & 15;
        fus[idx] = fmaxf(loc[(((size_t)b * 64 + c) * 16 + r) * 16 + p] + gvs[c], 0.f);
    }
    __syncthreads();
    // bg 1x1: thread t -> pixel p=t&15, co = (t>>4) + 16*j, j=0..5; weights from LDS
    {
        int p = t & 15, cg = t >> 4;
        float acc6[6];
        #pragma unroll
        for (int j = 0; j < 6; j++) acc6[j] = bgb[cg + (j << 4)];
        #pragma unroll 8
        for (int k = 0; k < 64; k++) {
            float f = fus[k * 16 + p];
            #pragma unroll
            for (int j = 0; j < 6; j++)
                acc6[j] += bgws[(cg + (j << 4)) * 65 + k] * f;
        }
        #pragma unroll
        for (int j = 0; j < 6; j++) {
            int co = cg + (j << 4);
            int c12 = co >> 3, d = co & 7;
            grid_r[(((((size_t)b * 8 + d) * 16 + r) * 16 + p) * 12) + c12] = acc6[j];
        }
    }
}

// ------- fused guide (1x1 convs + sigmoid) + trilinear slice + affine apply -------
__global__ void guide_slice(const float* __restrict__ fr, const float* __restrict__ grid_r,
                            const float* __restrict__ guw0, const float* __restrict__ gub0,
                            const float* __restrict__ guw1, const float* __restrict__ gub1,
                            float* __restrict__ gd_out, float* __restrict__ fin_out)
{
    const int W = 1024;
    int x = blockIdx.x * 64 + (threadIdx.x & 63);
    int y = blockIdx.y * 4 + (threadIdx.x >> 6);
    int b = blockIdx.z;
    int pix = y * W + x;

    const float* frb = fr + (size_t)b * 3 * HW_;
    float r  = frb[pix];
    float g  = frb[HW_ + pix];
    float bl = frb[2 * HW_ + pix];

    float s = gub1[0];
    #pragma unroll
    for (int c = 0; c < 16; c++) {
        float h = guw0[c * 3] * r + guw0[c * 3 + 1] * g + guw0[c * 3 + 2] * bl + gub0[c];
        h = fmaxf(h, 0.f);
        s += guw1[c] * h;
    }
    float gd = 1.f / (1.f + expf(-s));
    gd_out[(size_t)b * HW_ + pix] = gd;

    float xs = (x + 0.5f) * (1.f / 64.f) - 0.5f;
    float ys = (y + 0.5f) * (1.f / 64.f) - 0.5f;
    float fx = floorf(xs), fy = floorf(ys);
    int x0 = min(max((int)fx, 0), 15); int x1 = min(x0 + 1, 15);
    int y0 = min(max((int)fy, 0), 15); int y1 = min(y0 + 1, 15);
    float wx = xs - fx, wy = ys - fy;

    float gz = gd * 8.f - 0.5f;
    float fz = floorf(gz);
    int z0 = min(max((int)fz, 0), 7); int z1 = min(z0 + 1, 7);
    float wz = gz - fz;

    float acc[12];
    #pragma unroll
    for (int c = 0; c < 12; c++) acc[c] = 0.f;

    const float* gb = grid_r + (size_t)b * 8 * 16 * 16 * 12;
    #pragma unroll
    for (int zi = 0; zi < 2; zi++) {
        int z = zi ? z1 : z0;
        float wzf = zi ? wz : 1.f - wz;
        #pragma unroll
        for (int yi = 0; yi < 2; yi++) {
            int yy = yi ? y1 : y0;
            float wyf = wzf * (yi ? wy : 1.f - wy);
            #pragma unroll
            for (int xi = 0; xi < 2; xi++) {
                int xx = xi ? x1 : x0;
                float wf = wyf * (xi ? wx : 1.f - wx);
                const float4* p = (const float4*)(gb + ((z * 16 + yy) * 16 + xx) * 12);
                float4 a0 = p[0], a1 = p[1], a2 = p[2];
                acc[0] += wf * a0.x; acc[1]  += wf * a0.y; acc[2]  += wf * a0.z; acc[3]  += wf * a0.w;
                acc[4] += wf * a1.x; acc[5]  += wf * a1.y; acc[6]  += wf * a1.z; acc[7]  += wf * a1.w;
                acc[8] += wf * a2.x; acc[9]  += wf * a2.y; acc[10] += wf * a2.z; acc[11] += wf * a2.w;
            }
        }
    }

    float o0 = acc[0] * r + acc[1] * g + acc[2]  * bl + acc[3];
    float o1 = acc[4] * r + acc[5] * g + acc[6]  * bl + acc[7];
    float o2 = acc[8] * r + acc[9] * g + acc[10] * bl + acc[11];
    float* fb = fin_out + (size_t)b * 3 * HW_;
    fb[pix] = o0; fb[HW_ + pix] = o1; fb[2 * HW_ + pix] = o2;
}

extern "C" void kernel_launch(void* const* d_in, const int* in_sizes, int n_in,
                              void* d_out, int out_size, void* d_ws, size_t ws_size,
                              hipStream_t stream) {
    const float* lr   = (const float*)d_in[0];
    const float* fr   = (const float*)d_in[1];
    const float* sw0  = (const float*)d_in[2];  const float* sb0 = (const float*)d_in[3];
    const float* sw1  = (const float*)d_in[4];  const float* sb1 = (const float*)d_in[5];
    const float* sw2  = (const float*)d_in[6];  const float* sb2 = (const float*)d_in[7];
    const float* sw3  = (const float*)d_in[8];  const float* sb3 = (const float*)d_in[9];
    const float* lw0  = (const float*)d_in[10]; const float* lb0 = (const float*)d_in[11];
    const float* lw1  = (const float*)d_in[12]; const float* lb1 = (const float*)d_in[13];
    const float* gcw0 = (const float*)d_in[14]; const float* gcb0 = (const float*)d_in[15];
    const float* gcw1 = (const float*)d_in[16]; const float* gcb1 = (const float*)d_in[17];
    const float* fcw0 = (const float*)d_in[18]; const float* fcb0 = (const float*)d_in[19];
    const float* fcw1 = (const float*)d_in[20]; const float* fcb1 = (const float*)d_in[21];
    const float* fcw2 = (const float*)d_in[22]; const float* fcb2 = (const float*)d_in[23];
    const float* bgw  = (const float*)d_in[24]; const float* bgb = (const float*)d_in[25];
    const float* guw0 = (const float*)d_in[26]; const float* gub0 = (const float*)d_in[27];
    const float* guw1 = (const float*)d_in[28]; const float* gub1 = (const float*)d_in[29];

    float* ws = (float*)d_ws;
    float* ws1    = ws;            // [2,16,64,64]   131072
    float* ws3    = ws + 131072;   // [2,64,16,16]   32768
    float* loc0   = ws + 163840;   // [2,64,16,16]   32768
    float* loc    = ws + 196608;   // [2,64,16,16]   32768
    float* g0     = ws + 229376;   // [2,64,8,8]     8192
    float* v      = ws + 237568;   // [2,1024]       2048
    float* h0     = ws + 239616;   // [2,256]        512
    float* h1     = ws + 240128;   // [2,128]        256
    float* grid_r = ws + 240384;   // [2,8,16,16,12] 49152

    float* gd_out  = (float*)d_out;             // [2,1024,1024]
    float* fin_out = (float*)d_out + 2 * HW_;   // [2,3,1024,1024]

    const int B = 2;

    k_s0s1<<<dim3(256, B), 256, 0, stream>>>(lr, sw0, sb0, sw1, sb1, ws1);
    k_s2s3<<<dim3(64, B), 256, 0, stream>>>(ws1, sw2, sb2, sw3, sb3, ws3);
    k_loc0_gc0<<<dim3(10, 64, B), 256, 0, stream>>>(ws3, lw0, lb0, loc0, gcw0, gcb0, g0);
    k_loc1_gc1<<<dim3(9, 64, B), 256, 0, stream>>>(loc0, lw1, lb1, loc, g0, gcw1, gcb1, v);
    k_fc0<<<dim3(128), 256, 0, stream>>>(v, fcw0, fcb0, h0);
    k_fc1<<<dim3(8, B), 256, 0, stream>>>(h0, fcw1, fcb1, h1);
    k_fc2bg<<<dim3(16, B), 256, 0, stream>>>(h1, fcw2, fcb2, loc, bgw, bgb, grid_r);
    guide_slice<<<dim3(16, 256, B), 256, 0, stream>>>(
        fr, grid_r, guw0, gub0, guw1, gub1, gd_out, fin_out);
}

// Round 7
// 125.978 us; speedup vs baseline: 1.8017x; 1.0893x over previous
//
#include <hip/hip_runtime.h>
#include <math.h>

#define HW_ (1024*1024)

__device__ __forceinline__ float wave_red(float a) {
    a += __shfl_xor(a, 1);  a += __shfl_xor(a, 2);  a += __shfl_xor(a, 4);
    a += __shfl_xor(a, 8);  a += __shfl_xor(a, 16); a += __shfl_xor(a, 32);
    return a;
}

// ---------------- fused s0 (3->8, 256^2->128^2) + s1 (8->16, ->64^2) ----------------
// grid (256, B): each block computes a 4x4 tile of s1 output (all 16 ch).
__global__ void k_s0s1(const float* __restrict__ lr, const float* __restrict__ sw0,
                       const float* __restrict__ sb0, const float* __restrict__ sw1,
                       const float* __restrict__ sb1, float* __restrict__ ws1)
{
    __shared__ float s0s[8 * 9 * 10];    // [c][y][x pad10]
    __shared__ float w1s[16 * 8 * 9];    // 1152
    int b = blockIdx.y;
    int ty = blockIdx.x >> 4, tx = blockIdx.x & 15;
    int t = threadIdx.x;

    for (int i = t; i < 1152; i += 256) w1s[i] = sw1[i];
    for (int idx = t; idx < 648; idx += 256) {
        int c = idx / 81, rem = idx % 81, y = rem / 9, x = rem % 9;
        int gy = 8 * ty - 1 + y, gx = 8 * tx - 1 + x;    // s0 output coords
        float val = 0.f;
        if ((unsigned)gy < 128u && (unsigned)gx < 128u) {
            float acc = sb0[c];
            const float* wp = sw0 + c * 27;
            #pragma unroll
            for (int ci = 0; ci < 3; ci++) {
                const float* ic = lr + (((size_t)b * 3 + ci) << 16);
                #pragma unroll
                for (int kh = 0; kh < 3; kh++) {
                    int hi = 2 * gy - 1 + kh;
                    if ((unsigned)hi >= 256u) continue;
                    #pragma unroll
                    for (int kw = 0; kw < 3; kw++) {
                        int wi = 2 * gx - 1 + kw;
                        if ((unsigned)wi >= 256u) continue;
                        acc += ic[(hi << 8) + wi] * wp[(ci * 3 + kh) * 3 + kw];
                    }
                }
            }
            val = fmaxf(acc, 0.f);
        }
        s0s[c * 90 + y * 10 + x] = val;
    }
    __syncthreads();

    {   // 256 outputs: 16ch x 4 x 4
        int c = t >> 4, y = (t >> 2) & 3, x = t & 3;
        float acc = sb1[c];
        const float* wp = w1s + c * 72;
        #pragma unroll
        for (int ci = 0; ci < 8; ci++) {
            const float* sp = s0s + ci * 90;
            #pragma unroll
            for (int kh = 0; kh < 3; kh++)
                #pragma unroll
                for (int kw = 0; kw < 3; kw++)
                    acc += sp[(2 * y + kh) * 10 + (2 * x + kw)] * wp[ci * 9 + kh * 3 + kw];
        }
        ws1[(((size_t)b * 16 + c) * 64 + 4 * ty + y) * 64 + 4 * tx + x] = fmaxf(acc, 0.f);
    }
}

// ---------------- fused s2 (16->32, 64^2->32^2) + s3 (32->64, ->16^2) ----------------
// grid (64, B): each block computes a 2x2 tile of s3 output (all 64 ch).
__global__ void k_s2s3(const float* __restrict__ ws1, const float* __restrict__ sw2,
                       const float* __restrict__ sb2, const float* __restrict__ sw3,
                       const float* __restrict__ sb3, float* __restrict__ ws3)
{
    __shared__ float w1t[16 * 132];      // ws1 tile [ci][11][12]
    __shared__ float wbuf[4672];         // sw2 (4608) then sw3 chunk (64 rows x pad73)
    __shared__ float s2s[800];           // [32][5][5]
    int b = blockIdx.y;
    int ty = blockIdx.x >> 3, tx = blockIdx.x & 7;
    int t = threadIdx.x;

    for (int i = t; i < 4608; i += 256) wbuf[i] = sw2[i];
    for (int idx = t; idx < 16 * 121; idx += 256) {
        int ci = idx / 121, rem = idx % 121, y = rem / 11, x = rem % 11;
        int gy = 8 * ty - 3 + y, gx = 8 * tx - 3 + x;    // ws1 coords
        float val = 0.f;
        if ((unsigned)gy < 64u && (unsigned)gx < 64u)
            val = ws1[(((size_t)b * 16 + ci) << 12) + (gy << 6) + gx];
        w1t[ci * 132 + y * 12 + x] = val;
    }
    __syncthreads();

    for (int idx = t; idx < 800; idx += 256) {
        int c = idx / 25, rem = idx % 25, y = rem / 5, x = rem % 5;
        int gy = 4 * ty - 1 + y, gx = 4 * tx - 1 + x;    // s2 output coords
        float val = 0.f;
        if ((unsigned)gy < 32u && (unsigned)gx < 32u) {
            float acc = sb2[c];
            const float* wp = wbuf + c * 144;
            #pragma unroll
            for (int ci = 0; ci < 16; ci++) {
                const float* sp = w1t + ci * 132;
                #pragma unroll
                for (int kh = 0; kh < 3; kh++)
                    #pragma unroll
                    for (int kw = 0; kw < 3; kw++)
                        acc += sp[(2 * y + kh) * 12 + (2 * x + kw)] * wp[ci * 9 + kh * 3 + kw];
            }
            val = fmaxf(acc, 0.f);
        }
        s2s[idx] = val;
    }
    __syncthreads();

    // s3 stage: one output per thread (64ch x 2 x 2), sw3 via LDS in 4 ci-chunks of 8
    int c = t >> 2, y = (t >> 1) & 1, x = t & 1;
    float acc = sb3[c];
    for (int cc = 0; cc < 4; cc++) {
        for (int i = t; i < 4608; i += 256) {
            int co = i / 72, rem = i % 72;
            wbuf[co * 73 + rem] = sw3[co * 288 + cc * 72 + rem];
        }
        __syncthreads();
        const float* wp = wbuf + c * 73;
        #pragma unroll
        for (int ci8 = 0; ci8 < 8; ci8++) {
            const float* sp = s2s + (cc * 8 + ci8) * 25;
            #pragma unroll
            for (int kh = 0; kh < 3; kh++)
                #pragma unroll
                for (int kw = 0; kw < 3; kw++)
                    acc += sp[(2 * y + kh) * 5 + (2 * x + kw)] * wp[ci8 * 9 + kh * 3 + kw];
        }
        __syncthreads();
    }
    ws3[(((size_t)b * 64 + c) * 16 + 2 * ty + y) * 16 + 2 * tx + x] = fmaxf(acc, 0.f);
}

// ---- lw0 || gcw0, full input map in LDS (col-padded [64][16][18]). grid (80, B) ----
// x<64: loc0 co=x (1 px/thread). x>=64: gc0, 4 co per block.
__global__ void k_loc0_gc0(const float* __restrict__ ws3,
                           const float* __restrict__ lw0, const float* __restrict__ lb0,
                           float* __restrict__ loc0,
                           const float* __restrict__ gcw0, const float* __restrict__ gcb0,
                           float* __restrict__ g0)
{
    __shared__ float smem[20736];        // inp 18432 + gc weights 2304
    float* inp = smem;
    float* wgt = smem + 18432;
    int b = blockIdx.y, t = threadIdx.x;

    // zero the two pad columns of each row (disjoint from interior fill)
    for (int i = t; i < 2048; i += 256) {
        int ci = i >> 5, rem = i & 31;
        inp[ci * 288 + (rem >> 1) * 18 + (rem & 1) * 17] = 0.f;
    }
    {   // coalesced f4 load of full ws3[b] -> padded LDS
        const float4* src = (const float4*)(ws3 + ((size_t)b << 14));
        #pragma unroll
        for (int k = 0; k < 16; k++) {
            int i = t + (k << 8);
            float4 vv = src[i];
            int flat = i << 2;
            float* d = inp + (flat >> 8) * 288 + ((flat >> 4) & 15) * 18 + (flat & 15) + 1;
            d[0] = vv.x; d[1] = vv.y; d[2] = vv.z; d[3] = vv.w;
        }
    }
    if (blockIdx.x < 64) {
        __syncthreads();
        int co = blockIdx.x;
        int ho = t >> 4, wo = t & 15;
        const float* wb = lw0 + co * 576;      // uniform -> scalar loads
        float acc = lb0[co];
        for (int ci = 0; ci < 64; ci++) {
            const float* ip = inp + ci * 288 + wo;
            const float* wr = wb + ci * 9;
            #pragma unroll
            for (int kh = 0; kh < 3; kh++) {
                int hi = ho - 1 + kh;
                if ((unsigned)hi < 16u) {
                    const float* q = ip + hi * 18;
                    acc = fmaf(q[0], wr[kh * 3 + 0], acc);
                    acc = fmaf(q[1], wr[kh * 3 + 1], acc);
                    acc = fmaf(q[2], wr[kh * 3 + 2], acc);
                }
            }
        }
        loc0[((size_t)(b * 64 + co) << 8) + t] = fmaxf(acc, 0.f);
    } else {
        int cb = (blockIdx.x - 64) << 2;
        for (int i = t; i < 2304; i += 256) wgt[i] = gcw0[cb * 576 + i];
        __syncthreads();
        int sub = t >> 6, co = cb + sub;
        int px = t & 63, ho = px >> 3, wo = px & 7;
        const float* wb = wgt + sub * 576;
        float acc = gcb0[co];
        for (int ci = 0; ci < 64; ci++) {
            const float* ip = inp + ci * 288 + (wo << 1);
            const float* wr = wb + ci * 9;
            #pragma unroll
            for (int kh = 0; kh < 3; kh++) {
                int hi = (ho << 1) - 1 + kh;
                if ((unsigned)hi < 16u) {
                    const float* q = ip + hi * 18;
                    acc = fmaf(q[0], wr[kh * 3 + 0], acc);
                    acc = fmaf(q[1], wr[kh * 3 + 1], acc);
                    acc = fmaf(q[2], wr[kh * 3 + 2], acc);
                }
            }
        }
        g0[((size_t)(b * 64 + co) << 6) + px] = fmaxf(acc, 0.f);
    }
}

// ---- lw1 (no relu) || gcw1 (->v reshape order). grid (68, B) ----
__global__ void k_loc1_gc1(const float* __restrict__ loc0,
                           const float* __restrict__ lw1, const float* __restrict__ lb1,
                           float* __restrict__ loc,
                           const float* __restrict__ g0,
                           const float* __restrict__ gcw1, const float* __restrict__ gcb1,
                           float* __restrict__ v)
{
    __shared__ float smem[18432];
    int b = blockIdx.y, t = threadIdx.x;
    if (blockIdx.x < 64) {
        float* inp = smem;                 // [64][16][18]
        for (int i = t; i < 2048; i += 256) {
            int ci = i >> 5, rem = i & 31;
            inp[ci * 288 + (rem >> 1) * 18 + (rem & 1) * 17] = 0.f;
        }
        const float4* src = (const float4*)(loc0 + ((size_t)b << 14));
        #pragma unroll
        for (int k = 0; k < 16; k++) {
            int i = t + (k << 8);
            float4 vv = src[i];
            int flat = i << 2;
            float* d = inp + (flat >> 8) * 288 + ((flat >> 4) & 15) * 18 + (flat & 15) + 1;
            d[0] = vv.x; d[1] = vv.y; d[2] = vv.z; d[3] = vv.w;
        }
        __syncthreads();
        int co = blockIdx.x;
        int ho = t >> 4, wo = t & 15;
        const float* wb = lw1 + co * 576;
        float acc = lb1[co];
        for (int ci = 0; ci < 64; ci++) {
            const float* ip = inp + ci * 288 + wo;
            const float* wr = wb + ci * 9;
            #pragma unroll
            for (int kh = 0; kh < 3; kh++) {
                int hi = ho - 1 + kh;
                if ((unsigned)hi < 16u) {
                    const float* q = ip + hi * 18;
                    acc = fmaf(q[0], wr[kh * 3 + 0], acc);
                    acc = fmaf(q[1], wr[kh * 3 + 1], acc);
                    acc = fmaf(q[2], wr[kh * 3 + 2], acc);
                }
            }
        }
        loc[((size_t)(b * 64 + co) << 8) + t] = acc;   // no relu
    } else {
        float* inp = smem;                 // [64][8][10] = 5120
        float* wgt = smem + 5120;          // 16co x 576 = 9216
        int cb = (blockIdx.x - 64) << 4;
        for (int i = t; i < 1024; i += 256) {
            int ci = i >> 4, rem = i & 15;
            inp[ci * 80 + (rem >> 1) * 10 + (rem & 1) * 9] = 0.f;
        }
        const float4* src = (const float4*)(g0 + ((size_t)b << 12));
        #pragma unroll
        for (int k = 0; k < 4; k++) {
            int i = t + (k << 8);
            float4 vv = src[i];
            int flat = i << 2;
            float* d = inp + (flat >> 6) * 80 + ((flat >> 3) & 7) * 10 + (flat & 7) + 1;
            d[0] = vv.x; d[1] = vv.y; d[2] = vv.z; d[3] = vv.w;
        }
        for (int i = t; i < 9216; i += 256) wgt[i] = gcw1[cb * 576 + i];
        __syncthreads();
        int sub = t >> 4, co = cb + sub;
        int px = t & 15, ho = px >> 2, wo = px & 3;
        const float* wb = wgt + sub * 576;
        float acc = gcb1[co];
        for (int ci = 0; ci < 64; ci++) {
            const float* ip = inp + ci * 80 + (wo << 1);
            const float* wr = wb + ci * 9;
            #pragma unroll
            for (int kh = 0; kh < 3; kh++) {
                int hi = (ho << 1) - 1 + kh;
                if ((unsigned)hi < 8u) {
                    const float* q = ip + hi * 10;
                    acc = fmaf(q[0], wr[kh * 3 + 0], acc);
                    acc = fmaf(q[1], wr[kh * 3 + 1], acc);
                    acc = fmaf(q[2], wr[kh * 3 + 2], acc);
                }
            }
        }
        v[((size_t)b << 10) + (co << 4) + px] = fmaxf(acc, 0.f);
    }
}

// -------- FC0: wave-per-output GEMV 1024 -> 256, relu. grid 128 x 256thr --------
__global__ void k_fc0(const float* __restrict__ in, const float* __restrict__ w,
                      const float* __restrict__ bias, float* __restrict__ out)
{
    int gw = (blockIdx.x * blockDim.x + threadIdx.x) >> 6;   // [0, 512)
    int lane = threadIdx.x & 63;
    int b = gw >> 8, o = gw & 255;
    const float4* wr = (const float4*)(w + o * 1024);
    const float4* vr = (const float4*)(in + b * 1024);
    float acc = 0.f;
    #pragma unroll
    for (int i = 0; i < 4; i++) {
        float4 a = wr[i * 64 + lane];
        float4 x = vr[i * 64 + lane];
        acc += a.x * x.x + a.y * x.y + a.z * x.z + a.w * x.w;
    }
    acc = wave_red(acc);
    if (lane == 0) out[b * 256 + o] = fmaxf(acc + bias[o], 0.f);
}

// -------- FC1: 256 -> 128, relu. grid (8, B): block j owns outputs [16j, 16j+16) --------
__global__ void k_fc1(const float* __restrict__ h0, const float* __restrict__ fcw1,
                      const float* __restrict__ fcb1, float* __restrict__ h1)
{
    __shared__ float h0s[256];
    int b = blockIdx.y, j = blockIdx.x;
    int t = threadIdx.x, lane = t & 63, wv = t >> 6;
    h0s[t] = h0[b * 256 + t];
    __syncthreads();
    float4 x = ((float4*)h0s)[lane];
    #pragma unroll
    for (int i = 0; i < 4; i++) {
        int o = j * 16 + wv * 4 + i;
        float4 a = ((const float4*)(fcw1 + o * 256))[lane];
        float acc = a.x * x.x + a.y * x.y + a.z * x.z + a.w * x.w;
        acc = wave_red(acc);
        if (lane == 0) h1[b * 128 + o] = fmaxf(acc + fcb1[o], 0.f);
    }
}

// ------- fc2 (redundant, coalesced) + fusion + 1x1 bg conv (bgw in LDS, pad-65) -------
__global__ void k_fc2bg(const float* __restrict__ h1in,
                        const float* __restrict__ fcw2, const float* __restrict__ fcb2,
                        const float* __restrict__ loc,
                        const float* __restrict__ bgw, const float* __restrict__ bgb,
                        float* __restrict__ grid_r)
{
    __shared__ float h1s[128];
    __shared__ float gvs[64];
    __shared__ float fus[1024];          // [64ch][16pix]
    __shared__ float bgws[96 * 65];      // pad-65 rows: conflict-free column reads
    int b = blockIdx.y, r = blockIdx.x;
    int t = threadIdx.x, lane = t & 63, wv = t >> 6;

    if (t < 128) h1s[t] = h1in[b * 128 + t];
    for (int i = t; i < 6144; i += 256) bgws[(i >> 6) * 65 + (i & 63)] = bgw[i];
    __syncthreads();

    {
        float2 x = ((float2*)h1s)[lane];
        #pragma unroll 4
        for (int i = 0; i < 16; i++) {
            int o = (wv << 4) + i;
            float2 a = ((const float2*)(fcw2 + o * 128))[lane];
            float acc = a.x * x.x + a.y * x.y;
            acc = wave_red(acc);
            if (lane == 0) gvs[o] = acc + fcb2[o];
        }
    }
    __syncthreads();
    #pragma unroll
    for (int i = 0; i < 4; i++) {
        int idx = t + (i << 8);
        int c = idx >> 4, p = idx & 15;
        fus[idx] = fmaxf(loc[(((size_t)b * 64 + c) * 16 + r) * 16 + p] + gvs[c], 0.f);
    }
    __syncthreads();
    {
        int p = t & 15, cg = t >> 4;
        float acc6[6];
        #pragma unroll
        for (int j = 0; j < 6; j++) acc6[j] = bgb[cg + (j << 4)];
        #pragma unroll 8
        for (int k = 0; k < 64; k++) {
            float f = fus[k * 16 + p];
            #pragma unroll
            for (int j = 0; j < 6; j++)
                acc6[j] += bgws[(cg + (j << 4)) * 65 + k] * f;
        }
        #pragma unroll
        for (int j = 0; j < 6; j++) {
            int co = cg + (j << 4);
            int c12 = co >> 3, d = co & 7;
            grid_r[(((((size_t)b * 8 + d) * 16 + r) * 16 + p) * 12) + c12] = acc6[j];
        }
    }
}

// ------- fused guide + slice + apply: one image row per block, 4 px/thread -------
// y-lerped grid row staged in LDS: gy[z][x][12].
__global__ void guide_slice(const float* __restrict__ fr, const float* __restrict__ grid_r,
                            const float* __restrict__ guw0, const float* __restrict__ gub0,
                            const float* __restrict__ guw1, const float* __restrict__ gub1,
                            float* __restrict__ gd_out, float* __restrict__ fin_out)
{
    __shared__ float gy[1536];           // [z=8][x=16][c=12]
    int y = blockIdx.x, b = blockIdx.y;
    int t = threadIdx.x;

    float ys = (y + 0.5f) * 0.015625f - 0.5f;
    float fy = floorf(ys);
    int y0 = min(max((int)fy, 0), 15), y1 = min(y0 + 1, 15);
    float wy = ys - fy;

    const float* gb = grid_r + (size_t)b * 24576;
    for (int i = t; i < 1536; i += 256) {
        int z = i / 192, rem = i - z * 192;
        float a = gb[z * 3072 + y0 * 192 + rem];
        float c = gb[z * 3072 + y1 * 192 + rem];
        gy[i] = a + wy * (c - a);
    }
    __syncthreads();

    int rowoff = (y << 10) + (t << 2);
    const float* frb = fr + (size_t)b * 3 * HW_;
    float4 R4 = *(const float4*)(frb + rowoff);
    float4 G4 = *(const float4*)(frb + HW_ + rowoff);
    float4 B4 = *(const float4*)(frb + 2 * HW_ + rowoff);
    float rr[4] = {R4.x, R4.y, R4.z, R4.w};
    float gg[4] = {G4.x, G4.y, G4.z, G4.w};
    float bb[4] = {B4.x, B4.y, B4.z, B4.w};
    float gdv[4], O0[4], O1[4], O2[4];

    #pragma unroll
    for (int j = 0; j < 4; j++) {
        float r = rr[j], g = gg[j], bl = bb[j];
        float s = gub1[0];
        #pragma unroll
        for (int c = 0; c < 16; c++) {
            float h = fmaf(guw0[c * 3], r, fmaf(guw0[c * 3 + 1], g,
                      fmaf(guw0[c * 3 + 2], bl, gub0[c])));
            s = fmaf(guw1[c], fmaxf(h, 0.f), s);
        }
        float gd = 1.f / (1.f + __expf(-s));
        gdv[j] = gd;

        int x = (t << 2) + j;
        float xs = (x + 0.5f) * 0.015625f - 0.5f;
        float fx = floorf(xs);
        int x0 = min(max((int)fx, 0), 15), x1 = min(x0 + 1, 15);
        float wx = xs - fx;
        float gz = gd * 8.f - 0.5f;
        float fz = floorf(gz);
        int z0 = min(max((int)fz, 0), 7), z1 = min(z0 + 1, 7);
        float wz = gz - fz;

        float acc[12];
        #pragma unroll
        for (int c = 0; c < 12; c++) acc[c] = 0.f;
        #pragma unroll
        for (int zi = 0; zi < 2; zi++) {
            int z = zi ? z1 : z0;
            float wzf = zi ? wz : 1.f - wz;
            const float4* p0 = (const float4*)(gy + z * 192 + x0 * 12);
            const float4* p1 = (const float4*)(gy + z * 192 + x1 * 12);
            float w0 = wzf * (1.f - wx), w1 = wzf * wx;
            #pragma unroll
            for (int q = 0; q < 3; q++) {
                float4 a = p0[q], c4 = p1[q];
                acc[q * 4 + 0] += w0 * a.x + w1 * c4.x;
                acc[q * 4 + 1] += w0 * a.y + w1 * c4.y;
                acc[q * 4 + 2] += w0 * a.z + w1 * c4.z;
                acc[q * 4 + 3] += w0 * a.w + w1 * c4.w;
            }
        }
        O0[j] = fmaf(acc[0], r, fmaf(acc[1], g, fmaf(acc[2], bl, acc[3])));
        O1[j] = fmaf(acc[4], r, fmaf(acc[5], g, fmaf(acc[6], bl, acc[7])));
        O2[j] = fmaf(acc[8], r, fmaf(acc[9], g, fmaf(acc[10], bl, acc[11])));
    }

    *(float4*)(gd_out + (size_t)b * HW_ + rowoff) = make_float4(gdv[0], gdv[1], gdv[2], gdv[3]);
    float* fb = fin_out + (size_t)b * 3 * HW_;
    *(float4*)(fb + rowoff)           = make_float4(O0[0], O0[1], O0[2], O0[3]);
    *(float4*)(fb + HW_ + rowoff)     = make_float4(O1[0], O1[1], O1[2], O1[3]);
    *(float4*)(fb + 2 * HW_ + rowoff) = make_float4(O2[0], O2[1], O2[2], O2[3]);
}

extern "C" void kernel_launch(void* const* d_in, const int* in_sizes, int n_in,
                              void* d_out, int out_size, void* d_ws, size_t ws_size,
                              hipStream_t stream) {
    const float* lr   = (const float*)d_in[0];
    const float* fr   = (const float*)d_in[1];
    const float* sw0  = (const float*)d_in[2];  const float* sb0 = (const float*)d_in[3];
    const float* sw1  = (const float*)d_in[4];  const float* sb1 = (const float*)d_in[5];
    const float* sw2  = (const float*)d_in[6];  const float* sb2 = (const float*)d_in[7];
    const float* sw3  = (const float*)d_in[8];  const float* sb3 = (const float*)d_in[9];
    const float* lw0  = (const float*)d_in[10]; const float* lb0 = (const float*)d_in[11];
    const float* lw1  = (const float*)d_in[12]; const float* lb1 = (const float*)d_in[13];
    const float* gcw0 = (const float*)d_in[14]; const float* gcb0 = (const float*)d_in[15];
    const float* gcw1 = (const float*)d_in[16]; const float* gcb1 = (const float*)d_in[17];
    const float* fcw0 = (const float*)d_in[18]; const float* fcb0 = (const float*)d_in[19];
    const float* fcw1 = (const float*)d_in[20]; const float* fcb1 = (const float*)d_in[21];
    const float* fcw2 = (const float*)d_in[22]; const float* fcb2 = (const float*)d_in[23];
    const float* bgw  = (const float*)d_in[24]; const float* bgb = (const float*)d_in[25];
    const float* guw0 = (const float*)d_in[26]; const float* gub0 = (const float*)d_in[27];
    const float* guw1 = (const float*)d_in[28]; const float* gub1 = (const float*)d_in[29];

    float* ws = (float*)d_ws;
    float* ws1    = ws;            // [2,16,64,64]   131072
    float* ws3    = ws + 131072;   // [2,64,16,16]   32768
    float* loc0   = ws + 163840;   // [2,64,16,16]   32768
    float* loc    = ws + 196608;   // [2,64,16,16]   32768
    float* g0     = ws + 229376;   // [2,64,8,8]     8192
    float* v      = ws + 237568;   // [2,1024]       2048
    float* h0     = ws + 239616;   // [2,256]        512
    float* h1     = ws + 240128;   // [2,128]        256
    float* grid_r = ws + 240384;   // [2,8,16,16,12] 49152

    float* gd_out  = (float*)d_out;             // [2,1024,1024]
    float* fin_out = (float*)d_out + 2 * HW_;   // [2,3,1024,1024]

    const int B = 2;

    k_s0s1<<<dim3(256, B), 256, 0, stream>>>(lr, sw0, sb0, sw1, sb1, ws1);
    k_s2s3<<<dim3(64, B), 256, 0, stream>>>(ws1, sw2, sb2, sw3, sb3, ws3);
    k_loc0_gc0<<<dim3(80, B), 256, 0, stream>>>(ws3, lw0, lb0, loc0, gcw0, gcb0, g0);
    k_loc1_gc1<<<dim3(68, B), 256, 0, stream>>>(loc0, lw1, lb1, loc, g0, gcw1, gcb1, v);
    k_fc0<<<dim3(128), 256, 0, stream>>>(v, fcw0, fcb0, h0);
    k_fc1<<<dim3(8, B), 256, 0, stream>>>(h0, fcw1, fcb1, h1);
    k_fc2bg<<<dim3(16, B), 256, 0, stream>>>(h1, fcw2, fcb2, loc, bgw, bgb, grid_r);
    guide_slice<<<dim3(1024, B), 256, 0, stream>>>(
        fr, grid_r, guw0, gub0, guw1, gub1, gd_out, fin_out);
}